// Round 12
// baseline (87.619 us; speedup 1.0000x reference)
//
#include <hip/hip_runtime.h>

typedef _Float16 half8 __attribute__((ext_vector_type(8)));
typedef _Float16 half4 __attribute__((ext_vector_type(4)));
typedef float f32x4 __attribute__((ext_vector_type(4)));

#define S_LEN 2048
#define HDIM 64
#define NT (S_LEN / 64)
#define QRS 258
#define NBH 16
#define L2E 1.44269504f
#define TSTR 72

__device__ __forceinline__ void load_lds16(const void* g, void* l) {
    __builtin_amdgcn_global_load_lds(
        (const __attribute__((address_space(1))) unsigned int*)g,
        (__attribute__((address_space(3))) unsigned int*)l, 16, 0, 0);
}

// ---- pre-pass 1: K/V conversion (v7/v8 format, unchanged) --------------------------
// blocks 0..1023: K -> per-tile swizzled fp16 image:
//   (bh,t,kv,d) at byte (bh*32+t)*8192 + ((kv*128 + d*2) ^ ((kv&7)<<4))
// blocks 1024..1535: V -> pi-permuted transposed swizzled image:
//   chunk (d, u=4*kc+g): byte (d*128 + u*16)^((d&7)<<4);
//   content = {V[32kc+4g+r][d]}_{r=0..3} ++ {V[32kc+16+4g+r][d]}_{r=0..3}
__global__ __launch_bounds__(256)
void convert_kv_kernel(const float* __restrict__ Kg, const float* __restrict__ Vg,
                       _Float16* __restrict__ Kh, _Float16* __restrict__ Vp)
{
    __shared__ _Float16 tile[64 * TSTR];
    const int bid = blockIdx.x;
    const int tid = threadIdx.x;
    if (bid < 1024) {
        const int id = bid * 256 + tid;
        const int r  = id >> 3;
        const int d0 = (id & 7) * 8;
        const float* src = Kg + (size_t)r * HDIM + d0;
        f32x4 f0 = *(const f32x4*)(src);
        f32x4 f1 = *(const f32x4*)(src + 4);
        half8 h;
#pragma unroll
        for (int j = 0; j < 4; ++j) { h[j] = (_Float16)f0[j]; h[j+4] = (_Float16)f1[j]; }
        const int bh = r >> 11, kvg = r & 2047;
        const int t = kvg >> 6, kv = kvg & 63;
        const size_t blk = (size_t)(bh * NT + t) * 8192;
        const int off = (kv * 128 + d0 * 2) ^ ((kv & 7) << 4);
        *(half8*)((char*)Kh + blk + off) = h;
    } else {
        const int bt = bid - 1024;               // bh*32 + t
        const int bh = bt >> 5, t = bt & 31;
        {
            const int kv = tid >> 2;
            const int d0 = (tid & 3) * 16;
            const float* src = Vg + ((size_t)bh * S_LEN + t * 64 + kv) * HDIM + d0;
            f32x4 f0 = *(const f32x4*)(src);
            f32x4 f1 = *(const f32x4*)(src + 4);
            f32x4 f2 = *(const f32x4*)(src + 8);
            f32x4 f3 = *(const f32x4*)(src + 12);
            half8 h0, h1;
#pragma unroll
            for (int j = 0; j < 4; ++j) {
                h0[j] = (_Float16)f0[j]; h0[j+4] = (_Float16)f1[j];
                h1[j] = (_Float16)f2[j]; h1[j+4] = (_Float16)f3[j];
            }
            *(half8*)&tile[kv * TSTR + d0]     = h0;
            *(half8*)&tile[kv * TSTR + d0 + 8] = h1;
        }
        __syncthreads();
        {
            const int dp = tid >> 2;
            const int u0 = (tid & 3) * 2;
            char* base = (char*)Vp + (size_t)bt * 8192;
            const int dsw = (dp & 7) << 4;
#pragma unroll
            for (int ui = 0; ui < 2; ++ui) {
                const int u  = u0 + ui;
                const int kc = u >> 2, gg = u & 3;
                half8 ch;
#pragma unroll
                for (int r = 0; r < 4; ++r) {
                    ch[r]     = tile[(32*kc + 4*gg + r)      * TSTR + dp];
                    ch[4 + r] = tile[(32*kc + 16 + 4*gg + r) * TSTR + dp];
                }
                *(half8*)(base + ((dp * 128 + u * 16) ^ dsw)) = ch;
            }
        }
    }
}

// ---- pre-pass 2: Qrel = (Q/8) @ rel_table^T -> global fp16 [32768][258] -------------
__global__ __launch_bounds__(256)
void qrel_kernel(const float* __restrict__ Qg, const float* __restrict__ RELg,
                 _Float16* __restrict__ Qrel_g)
{
    const int b = blockIdx.x;                // rows [64b, 64b+64)
    const int tid = threadIdx.x;
    const int wave = tid >> 6;
    const int lane = tid & 63;
    const int c = lane & 15, g = lane >> 4;

    const int row = b * 64 + wave * 16 + c;
    half8 aq[2];
#pragma unroll
    for (int kc = 0; kc < 2; ++kc) {
        const float* src = Qg + (size_t)row * HDIM + kc * 32 + g * 8;
        f32x4 f0 = *(const f32x4*)(src);
        f32x4 f1 = *(const f32x4*)(src + 4);
        half8 h;
#pragma unroll
        for (int j = 0; j < 4; ++j) {
            h[j]     = (_Float16)(f0[j] * 0.125f);
            h[j + 4] = (_Float16)(f1[j] * 0.125f);
        }
        aq[kc] = h;
    }
#pragma unroll 1
    for (int t = 0; t < 17; ++t) {
        f32x4 acc = {0.f, 0.f, 0.f, 0.f};
        int r = t * 16 + c;
        if (r > 256) r = 256;
#pragma unroll
        for (int kc = 0; kc < 2; ++kc) {
            const float* src = RELg + (size_t)r * HDIM + kc * 32 + g * 8;
            f32x4 f0 = *(const f32x4*)(src);
            f32x4 f1 = *(const f32x4*)(src + 4);
            half8 bb;
#pragma unroll
            for (int j = 0; j < 4; ++j) { bb[j] = (_Float16)f0[j]; bb[j+4] = (_Float16)f1[j]; }
            acc = __builtin_amdgcn_mfma_f32_16x16x32_f16(aq[kc], bb, acc, 0, 0, 0);
        }
        const int col = t * 16 + c;
        if (col <= 256) {
#pragma unroll
            for (int reg = 0; reg < 4; ++reg)
                Qrel_g[(size_t)(b * 64 + wave * 16 + 4 * g + reg) * QRS + col] = (_Float16)acc[reg];
        }
    }
}

// ---- main attention kernel (v12: QBLK=32, 4 blocks/CU, 32 waves/CU) ----------------
// 8 waves = 2 qs (16 q-rows) x 4 ks (16 kv rows per 64-tile).
// Swapped QK (16x16x32): per-lane q=c, kv=4g+r -> lane-local softmax.
// PV via 16x16x16, A-operand = sacc registers directly (pi-image half4 slices).
__global__ __launch_bounds__(512, 8)
void relattn_v12(const float* __restrict__ Qg, const _Float16* __restrict__ Qrel_g,
                 const _Float16* __restrict__ Kh, const _Float16* __restrict__ Vp,
                 float* __restrict__ Og)
{
    __shared__ __attribute__((aligned(16))) _Float16 Kbuf[2][4096];   // 16 KB (Opart at end)
    __shared__ __attribute__((aligned(16))) _Float16 Vbuf[2][4096];   // 16 KB
    __shared__ float MLm[8][16];
    __shared__ float MLl[8][16];

    const int tid  = threadIdx.x;
    const int wave = tid >> 6;
    const int lane = tid & 63;
    const int c  = lane & 15;
    const int g  = lane >> 4;
    const int qs = wave >> 2;      // 0..1 : q rows [16qs, 16qs+16)
    const int ks = wave & 3;       // 0..3 : kv rows [16ks, 16ks+16) of each tile

    const int wk  = ((blockIdx.x & 7) << 7) + (blockIdx.x >> 3);  // 1024 % 8 == 0
    const int bh  = wk >> 6;
    const int q0b = (wk & 63) * 32;
    const size_t hoff = (size_t)bh * S_LEN * HDIM;

    const char* kimg = (const char*)Kh + (size_t)bh * NT * 8192;
    const char* vimg = (const char*)Vp + (size_t)bh * NT * 8192;

    // ---- prologue: stage tile 0 ----
    load_lds16(kimg + tid * 16, (char*)&Kbuf[0][0] + tid * 16);
    load_lds16(vimg + tid * 16, (char*)&Vbuf[0][0] + tid * 16);

    // ---- Q fragment (B-operand, x0.125): Q[q0b+16qs+c][32kc+8g+j] ----
    const int qrow = q0b + 16 * qs + c;
    half8 bq[2];
#pragma unroll
    for (int kc = 0; kc < 2; ++kc) {
        const float* src = Qg + hoff + (size_t)qrow * HDIM + kc * 32 + g * 8;
        f32x4 f0 = *(const f32x4*)(src);
        f32x4 f1 = *(const f32x4*)(src + 4);
        half8 h;
#pragma unroll
        for (int j = 0; j < 4; ++j) {
            h[j]     = (_Float16)(f0[j] * 0.125f);
            h[j + 4] = (_Float16)(f1[j] * 0.125f);
        }
        bq[kc] = h;
    }

    // per-lane qrel row pointer (global) + off-band constants
    const _Float16* qrp = Qrel_g + (size_t)(bh * S_LEN + qrow) * QRS;
    const float bias_lo = (float)qrp[0];
    const float bias_hi = (float)qrp[256];

    // ---- loop-invariant LDS byte offsets ----
    const int r64 = 16 * ks + c;                       // K row within tile
    int koff[2];
#pragma unroll
    for (int kc = 0; kc < 2; ++kc)
        koff[kc] = (r64 * 128 + kc * 64 + g * 16) ^ ((r64 & 7) << 4);
    int voff[4];
#pragma unroll
    for (int dn = 0; dn < 4; ++dn) {
        const int d = 16 * dn + c;
        voff[dn] = (d * 128 + (4 * (ks >> 1) + g) * 16 + 8 * (ks & 1)) ^ ((d & 7) << 4);
    }

    float m = -1e30f, l = 0.f;
    f32x4 oacc[4];
#pragma unroll
    for (int i = 0; i < 4; ++i) oacc[i] = (f32x4){0.f, 0.f, 0.f, 0.f};

#pragma unroll 1
    for (int t = 0; t < NT; ++t) {
        const int b = t & 1;
        asm volatile("s_waitcnt vmcnt(0)" ::: "memory");
        __builtin_amdgcn_s_barrier();
        {
            const int tn = (t + 1 < NT) ? t + 1 : t;
            load_lds16(kimg + (size_t)tn * 8192 + tid * 16, (char*)&Kbuf[b ^ 1][0] + tid * 16);
            load_lds16(vimg + (size_t)tn * 8192 + tid * 16, (char*)&Vbuf[b ^ 1][0] + tid * 16);
        }

        // ---- QK: sacc[r] = S[kv = 64t+16ks+4g+r][q = qrow] ----
        const char* kb = (const char*)&Kbuf[b][0];
        half8 a0 = *(const half8*)(kb + koff[0]);
        half8 a1 = *(const half8*)(kb + koff[1]);
        f32x4 sacc = {0.f, 0.f, 0.f, 0.f};
        __builtin_amdgcn_s_setprio(1);
        sacc = __builtin_amdgcn_mfma_f32_16x16x32_f16(a0, bq[0], sacc, 0, 0, 0);
        sacc = __builtin_amdgcn_mfma_f32_16x16x32_f16(a1, bq[1], sacc, 0, 0, 0);
        __builtin_amdgcn_s_setprio(0);

        // ---- bias + per-row (lane-local) softmax ----
        float bias, lm;
        if (64 * t + 192 <= q0b) {
            bias = bias_lo;
            lm = fmaxf(fmaxf(sacc[0], sacc[1]), fmaxf(sacc[2], sacc[3])) + bias;
        } else if (64 * t >= q0b + 159) {
            bias = bias_hi;
            lm = fmaxf(fmaxf(sacc[0], sacc[1]), fmaxf(sacc[2], sacc[3])) + bias;
        } else {
            bias = 0.f;
            const int base_d = 64 * t + 16 * ks + 4 * g - qrow + 128;
            lm = -1e30f;
#pragma unroll
            for (int r = 0; r < 4; ++r) {
                int idx = base_d + r;
                idx = idx < 0 ? 0 : (idx > 256 ? 256 : idx);
                sacc[r] += (float)qrp[idx];
                lm = fmaxf(lm, sacc[r]);
            }
        }
        lm = fmaxf(lm, __shfl_xor(lm, 16, 64));
        lm = fmaxf(lm, __shfl_xor(lm, 32, 64));
        if (!__all(lm <= m + 8.f)) {
            const float mnew = fmaxf(m, lm);
            const float al = __builtin_amdgcn_exp2f((m - mnew) * L2E);
            m = mnew;
            l *= al;
#pragma unroll
            for (int r = 0; r < 4; ++r) {
                const float ar = __shfl(al, 4 * g + r, 64);
#pragma unroll
                for (int dn = 0; dn < 4; ++dn) oacc[dn][r] *= ar;
            }
        }
        const float fold = (bias - m) * L2E;
        half4 ap;
        float ps = 0.f;
#pragma unroll
        for (int r = 0; r < 4; ++r) {
            const float pv = __builtin_amdgcn_exp2f(fmaf(sacc[r], L2E, fold));
            ps += pv;
            ap[r] = (_Float16)pv;
        }
        ps += __shfl_xor(ps, 16, 64);
        ps += __shfl_xor(ps, 32, 64);
        l += ps;

        // ---- PV: oacc[dn] += P @ V (16x16x16, A = ap directly) ----
        const char* vb = (const char*)&Vbuf[b][0];
        half4 v0 = *(const half4*)(vb + voff[0]);
        half4 v1 = *(const half4*)(vb + voff[1]);
        half4 v2 = *(const half4*)(vb + voff[2]);
        half4 v3 = *(const half4*)(vb + voff[3]);
        __builtin_amdgcn_s_setprio(1);
        oacc[0] = __builtin_amdgcn_mfma_f32_16x16x16f16(ap, v0, oacc[0], 0, 0, 0);
        oacc[1] = __builtin_amdgcn_mfma_f32_16x16x16f16(ap, v1, oacc[1], 0, 0, 0);
        oacc[2] = __builtin_amdgcn_mfma_f32_16x16x16f16(ap, v2, oacc[2], 0, 0, 0);
        oacc[3] = __builtin_amdgcn_mfma_f32_16x16x16f16(ap, v3, oacc[3], 0, 0, 0);
        __builtin_amdgcn_s_setprio(0);
    }

    // ---- epilogue: 4-way ks merge in LDS (Opart reuses Kbuf, 16 KB) ----
    asm volatile("s_waitcnt vmcnt(0)" ::: "memory");
    __syncthreads();
    {
        char* Ob = (char*)&Kbuf[0][0];   // [ks][q 0..31][d 0..63] fp16, q-swizzled
#pragma unroll
        for (int r = 0; r < 4; ++r) {
            const int q = 16 * qs + 4 * g + r;
            const int qsw = (q & 7) << 4;
#pragma unroll
            for (int dn = 0; dn < 4; ++dn) {
                const int d = 16 * dn + c;
                *(_Float16*)(Ob + ks * 4096 + q * 128 + ((d * 2) ^ qsw)) = (_Float16)oacc[dn][r];
            }
        }
        if (g == 0) { MLm[wave][c] = m; MLl[wave][c] = l; }
        __syncthreads();

        const int q  = tid >> 4;             // 0..31
        const int d0 = (tid & 15) * 4;
        const int qs_ = q >> 4, qc = q & 15;
        const int qsw = (q & 7) << 4;
        float mm[4], ll[4];
#pragma unroll
        for (int k4 = 0; k4 < 4; ++k4) {
            mm[k4] = MLm[4 * qs_ + k4][qc];
            ll[k4] = MLl[4 * qs_ + k4][qc];
        }
        const float M = fmaxf(fmaxf(mm[0], mm[1]), fmaxf(mm[2], mm[3]));
        float wgt[4], den = 0.f;
#pragma unroll
        for (int k4 = 0; k4 < 4; ++k4) {
            wgt[k4] = __builtin_amdgcn_exp2f((mm[k4] - M) * L2E);
            den += wgt[k4] * ll[k4];
        }
        const float inv = 1.0f / den;
        float acc[4] = {0.f, 0.f, 0.f, 0.f};
        const char* Obr = (const char*)&Kbuf[0][0] + q * 128;
#pragma unroll
        for (int k4 = 0; k4 < 4; ++k4) {
            half4 o = *(const half4*)(Obr + k4 * 4096 + ((d0 * 2) ^ qsw));
#pragma unroll
            for (int j = 0; j < 4; ++j) acc[j] += (float)o[j] * wgt[k4];
        }
        f32x4 out;
#pragma unroll
        for (int j = 0; j < 4; ++j) out[j] = acc[j] * inv;
        *(f32x4*)(Og + hoff + (size_t)(q0b + q) * HDIM + d0) = out;
    }
}

// ---- mid fallback: R8 kernel (proven 53.7 us) ---------------------------------------
__global__ __launch_bounds__(512, 4)
void relattn_v8(const float* __restrict__ Qg, const float* __restrict__ RELg,
                const _Float16* __restrict__ Kh, const _Float16* __restrict__ Vp,
                float* __restrict__ Og)
{
    __shared__ __attribute__((aligned(16))) _Float16 Kbuf[3][4096];
    __shared__ __attribute__((aligned(16))) _Float16 Vbuf[2][4096];
    __shared__ __attribute__((aligned(16))) _Float16 Qrel[64 * QRS];
    __shared__ float MLds[2][64];
    __shared__ float LLds[2][64];

    const int tid  = threadIdx.x;
    const int wave = tid >> 6;
    const int lane = tid & 63;
    const int c  = lane & 15;
    const int g  = lane >> 4;
    const int qs = wave & 3;
    const int ks = wave >> 2;

    const int wk = ((blockIdx.x & 7) << 6) + (blockIdx.x >> 3);
    const int bh = wk >> 5;
    const int q0 = (wk & 31) * 64;
    const size_t hoff = (size_t)bh * S_LEN * HDIM;

    const char* kimg = (const char*)Kh + (size_t)bh * NT * 8192;
    const char* vimg = (const char*)Vp + (size_t)bh * NT * 8192;

    load_lds16(vimg + tid * 16, (char*)Vbuf + tid * 16);
    load_lds16(kimg + tid * 16, (char*)Kbuf + tid * 16);
    load_lds16(kimg + 8192 + tid * 16, (char*)&Kbuf[1][0] + tid * 16);

    const int qb0 = q0 + 16 * qs;
    half8 bq[2];
#pragma unroll
    for (int kc = 0; kc < 2; ++kc) {
        const float* src = Qg + hoff + (size_t)(qb0 + c) * HDIM + kc * 32 + g * 8;
        f32x4 f0 = *(const f32x4*)(src);
        f32x4 f1 = *(const f32x4*)(src + 4);
        half8 h;
#pragma unroll
        for (int j = 0; j < 4; ++j) {
            h[j]     = (_Float16)(f0[j] * 0.125f);
            h[j + 4] = (_Float16)(f1[j] * 0.125f);
        }
        bq[kc] = h;
    }

    if (ks == 0) {
#pragma unroll 1
        for (int t = 0; t < 17; ++t) {
            f32x4 acc = {0.f, 0.f, 0.f, 0.f};
            int r = t * 16 + c;
            if (r > 256) r = 256;
#pragma unroll
            for (int kc = 0; kc < 2; ++kc) {
                const float* src = RELg + (size_t)r * HDIM + kc * 32 + g * 8;
                f32x4 f0 = *(const f32x4*)(src);
                f32x4 f1 = *(const f32x4*)(src + 4);
                half8 b;
#pragma unroll
                for (int j = 0; j < 4; ++j) { b[j] = (_Float16)f0[j]; b[j+4] = (_Float16)f1[j]; }
                acc = __builtin_amdgcn_mfma_f32_16x16x32_f16(bq[kc], b, acc, 0, 0, 0);
            }
            const int col = t * 16 + c;
            if (col <= 256) {
#pragma unroll
                for (int reg = 0; reg < 4; ++reg)
                    Qrel[(16 * qs + 4 * g + reg) * QRS + col] = (_Float16)acc[reg];
            }
        }
    }
    __syncthreads();

    const _Float16* qr = &Qrel[(16 * qs + c) * QRS];
    const float bias_lo = (float)qr[0];
    const float bias_hi = (float)qr[256];

    const int swz = (c & 7) << 4;
    int akoff[2][2], voff[4];
#pragma unroll
    for (int n = 0; n < 2; ++n)
#pragma unroll
        for (int kc = 0; kc < 2; ++kc)
            akoff[n][kc] = (((32 * ks + 16 * n + c) * 128) + kc * 64 + g * 16) ^ swz;
#pragma unroll
    for (int dn = 0; dn < 4; ++dn)
        voff[dn] = (((16 * dn + c) * 128) + ks * 64 + g * 16) ^ swz;

    half8 ones;
#pragma unroll
    for (int j = 0; j < 8; ++j) ones[j] = (_Float16)1.0f;

    float m = -1e30f;
    f32x4 l_acc = {0.f, 0.f, 0.f, 0.f};
    f32x4 oacc[4];
#pragma unroll
    for (int i = 0; i < 4; ++i) oacc[i] = (f32x4){0.f, 0.f, 0.f, 0.f};

#define BODY(t, KB, VB, VBN, KBN) do {                                               \
        asm volatile("s_waitcnt vmcnt(1)" ::: "memory");                             \
        __builtin_amdgcn_s_barrier();                                                \
        {                                                                            \
            const int tv = ((t) + 1 < NT) ? (t) + 1 : NT - 1;                        \
            const int tk = ((t) + 2 < NT) ? (t) + 2 : NT - 1;                        \
            load_lds16(vimg + (size_t)tv * 8192 + tid * 16,                          \
                       (char*)&Vbuf[VBN][0] + tid * 16);                             \
            load_lds16(kimg + (size_t)tk * 8192 + tid * 16,                          \
                       (char*)&Kbuf[KBN][0] + tid * 16);                             \
        }                                                                            \
        const char* kb = (const char*)&Kbuf[KB][0];                                  \
        const char* vb = (const char*)&Vbuf[VB][0];                                  \
        const int kws = (t) * 64 + 32 * ks;                                          \
        half8 a00 = *(const half8*)(kb + akoff[0][0]);                               \
        half8 a01 = *(const half8*)(kb + akoff[0][1]);                               \
        half8 a10 = *(const half8*)(kb + akoff[1][0]);                               \
        half8 a11 = *(const half8*)(kb + akoff[1][1]);                               \
        f32x4 s0 = {0.f,0.f,0.f,0.f}, s1 = {0.f,0.f,0.f,0.f};                        \
        __builtin_amdgcn_s_setprio(1);                                               \
        s0 = __builtin_amdgcn_mfma_f32_16x16x32_f16(a00, bq[0], s0, 0, 0, 0);        \
        s1 = __builtin_amdgcn_mfma_f32_16x16x32_f16(a10, bq[0], s1, 0, 0, 0);        \
        s0 = __builtin_amdgcn_mfma_f32_16x16x32_f16(a01, bq[1], s0, 0, 0, 0);        \
        s1 = __builtin_amdgcn_mfma_f32_16x16x32_f16(a11, bq[1], s1, 0, 0, 0);        \
        __builtin_amdgcn_s_setprio(0);                                               \
        float bias = 0.f;                                                            \
        float lm;                                                                    \
        if (kws + 159 <= qb0) {                                                      \
            bias = bias_lo;                                                          \
            lm = fmaxf(fmaxf(fmaxf(s0[0], s0[1]), fmaxf(s0[2], s0[3])),              \
                       fmaxf(fmaxf(s1[0], s1[1]), fmaxf(s1[2], s1[3]))) + bias;      \
        } else if (kws >= qb0 + 143) {                                               \
            bias = bias_hi;                                                          \
            lm = fmaxf(fmaxf(fmaxf(s0[0], s0[1]), fmaxf(s0[2], s0[3])),              \
                       fmaxf(fmaxf(s1[0], s1[1]), fmaxf(s1[2], s1[3]))) + bias;      \
        } else {                                                                     \
            const int base_d = kws + 4 * g - (qb0 + c) + 128;                        \
            _Pragma("unroll")                                                        \
            for (int r = 0; r < 4; ++r) {                                            \
                int i0 = base_d + r;                                                 \
                i0 = i0 < 0 ? 0 : (i0 > 256 ? 256 : i0);                             \
                int i1 = base_d + 16 + r;                                            \
                i1 = i1 < 0 ? 0 : (i1 > 256 ? 256 : i1);                             \
                s0[r] += (float)qr[i0];                                              \
                s1[r] += (float)qr[i1];                                              \
            }                                                                        \
            lm = fmaxf(fmaxf(fmaxf(s0[0], s0[1]), fmaxf(s0[2], s0[3])),              \
                       fmaxf(fmaxf(s1[0], s1[1]), fmaxf(s1[2], s1[3])));             \
        }                                                                            \
        if (!__all(lm <= m + 8.f)) {                                                 \
            float mt = lm;                                                           \
            mt = fmaxf(mt, __shfl_xor(mt, 16, 64));                                  \
            mt = fmaxf(mt, __shfl_xor(mt, 32, 64));                                  \
            const float mnew = fmaxf(m, mt);                                         \
            const float al = __builtin_amdgcn_exp2f((m - mnew) * L2E);               \
            m = mnew;                                                                \
            _Pragma("unroll")                                                        \
            for (int r = 0; r < 4; ++r) {                                            \
                const float ar = __shfl(al, 20 * g + r, 64);                         \
                l_acc[r] *= ar;                                                      \
                _Pragma("unroll")                                                    \
                for (int dn = 0; dn < 4; ++dn) oacc[dn][r] *= ar;                    \
            }                                                                        \
        }                                                                            \
        const float fold = (bias - m) * L2E;                                         \
        half8 ap;                                                                    \
        _Pragma("unroll")                                                            \
        for (int r = 0; r < 4; ++r) {                                                \
            ap[r]     = (_Float16)__builtin_amdgcn_exp2f(fmaf(s0[r], L2E, fold));    \
            ap[4 + r] = (_Float16)__builtin_amdgcn_exp2f(fmaf(s1[r], L2E, fold));    \
        }                                                                            \
        half8 v0 = *(const half8*)(vb + voff[0]);                                    \
        half8 v1 = *(const half8*)(vb + voff[1]);                                    \
        half8 v2 = *(const half8*)(vb + voff[2]);                                    \
        half8 v3 = *(const half8*)(vb + voff[3]);                                    \
        __builtin_amdgcn_s_setprio(1);                                               \
        l_acc   = __builtin_amdgcn_mfma_f32_16x16x32_f16(ap, ones, l_acc, 0, 0, 0);  \
        oacc[0] = __builtin_amdgcn_mfma_f32_16x16x32_f16(ap, v0, oacc[0], 0, 0, 0);  \
        oacc[1] = __builtin_amdgcn_mfma_f32_16x16x32_f16(ap, v1, oacc[1], 0, 0, 0);  \
        oacc[2] = __builtin_amdgcn_mfma_f32_16x16x32_f16(ap, v2, oacc[2], 0, 0, 0);  \
        oacc[3] = __builtin_amdgcn_mfma_f32_16x16x32_f16(ap, v3, oacc[3], 0, 0, 0);  \
        __builtin_amdgcn_s_setprio(0);                                               \
    } while (0)

#pragma unroll 1
    for (int tt = 0; tt < 30; tt += 6) {
        BODY(tt + 0, 0, 0, 1, 2);
        BODY(tt + 1, 1, 1, 0, 0);
        BODY(tt + 2, 2, 0, 1, 1);
        BODY(tt + 3, 0, 1, 0, 2);
        BODY(tt + 4, 1, 0, 1, 0);
        BODY(tt + 5, 2, 1, 0, 1);
    }
    BODY(30, 0, 0, 1, 2);
    BODY(31, 1, 1, 0, 0);
#undef BODY

    asm volatile("s_waitcnt vmcnt(0)" ::: "memory");
    __syncthreads();
    {
        char* Ob = (char*)Kbuf;
#pragma unroll
        for (int r = 0; r < 4; ++r) {
            const int row = 16 * qs + 4 * g + r;
            const int rsw = (row & 7) << 4;
#pragma unroll
            for (int dn = 0; dn < 4; ++dn)
                *(_Float16*)(Ob + ks * 8192 + ((row * 128 + (16 * dn + c) * 2) ^ rsw))
                    = (_Float16)oacc[dn][r];
        }
        if (g == 0) MLds[ks][16 * qs + c] = m;
        if (c == 0) {
#pragma unroll
            for (int r = 0; r < 4; ++r)
                LLds[ks][16 * qs + 4 * g + r] = l_acc[r];
        }
        __syncthreads();

        const int row = 16 * qs + c;
        const int rsw = (c & 7) << 4;
        const float m0 = MLds[0][row], m1 = MLds[1][row];
        const float l0 = LLds[0][row], l1 = LLds[1][row];
        const float M  = fmaxf(m0, m1);
        const float w0 = __builtin_amdgcn_exp2f((m0 - M) * L2E);
        const float w1 = __builtin_amdgcn_exp2f((m1 - M) * L2E);
        const float inv = 1.0f / (l0 * w0 + l1 * w1);

        const int dof = 64 * ks + 16 * g;
        half8 o0 = *(const half8*)(Ob +        ((row * 128 + dof) ^ rsw));
        half8 o1 = *(const half8*)(Ob + 8192 + ((row * 128 + dof) ^ rsw));
        float* dst = Og + hoff + (size_t)(q0 + row) * HDIM + 32 * ks + 8 * g;
        f32x4 oA, oB;
#pragma unroll
        for (int j = 0; j < 4; ++j) {
            oA[j] = ((float)o0[j]     * w0 + (float)o1[j]     * w1) * inv;
            oB[j] = ((float)o0[4 + j] * w0 + (float)o1[4 + j] * w1) * inv;
        }
        *(f32x4*)dst = oA;
        *(f32x4*)(dst + 4) = oB;
    }
}

// ---- last-resort fallback (round-1 kernel) ------------------------------------------
__global__ __launch_bounds__(256, 2)
void relattn_v1(const float* __restrict__ Qg, const float* __restrict__ Kg,
                const float* __restrict__ Vg, const float* __restrict__ RELg,
                float* __restrict__ Og)
{
    __shared__ _Float16 Klds[64 * HDIM];
    __shared__ _Float16 Vt[HDIM * 64];
    __shared__ _Float16 Plds[4][16 * 64];
    __shared__ _Float16 Qrel[64 * QRS];

    const int tid  = threadIdx.x;
    const int wave = tid >> 6;
    const int lane = tid & 63;
    const int c = lane & 15;
    const int g = lane >> 4;

    const int bid = blockIdx.x;
    const int bh  = bid >> 5;
    const int q0  = (bid & 31) * 64;

    const size_t hoff = (size_t)bh * S_LEN * HDIM;
    const float* Qh = Qg + hoff;
    const float* Kh = Kg + hoff;
    const float* Vh = Vg + hoff;

    const int qrow_frag = q0 + wave * 16 + c;
    half8 aq[2];
#pragma unroll
    for (int kc = 0; kc < 2; ++kc) {
        const float* src = Qh + (size_t)qrow_frag * HDIM + kc * 32 + g * 8;
        f32x4 f0 = *(const f32x4*)(src);
        f32x4 f1 = *(const f32x4*)(src + 4);
        half8 h;
#pragma unroll
        for (int j = 0; j < 4; ++j) {
            h[j]     = (_Float16)(f0[j] * 0.125f);
            h[j + 4] = (_Float16)(f1[j] * 0.125f);
        }
        aq[kc] = h;
    }

#pragma unroll 1
    for (int t = 0; t < 17; ++t) {
        f32x4 acc = {0.f, 0.f, 0.f, 0.f};
        int r = t * 16 + c;
        if (r > 256) r = 256;
#pragma unroll
        for (int kc = 0; kc < 2; ++kc) {
            const float* src = RELg + (size_t)r * HDIM + kc * 32 + g * 8;
            f32x4 f0 = *(const f32x4*)(src);
            f32x4 f1 = *(const f32x4*)(src + 4);
            half8 b;
#pragma unroll
            for (int j = 0; j < 4; ++j) { b[j] = (_Float16)f0[j]; b[j+4] = (_Float16)f1[j]; }
            acc = __builtin_amdgcn_mfma_f32_16x16x32_f16(aq[kc], b, acc, 0, 0, 0);
        }
        const int col = t * 16 + c;
        if (col <= 256) {
#pragma unroll
            for (int reg = 0; reg < 4; ++reg)
                Qrel[(wave * 16 + 4 * g + reg) * QRS + col] = (_Float16)acc[reg];
        }
    }

    float mrow[4], lrow[4];
    f32x4 oacc[4];
#pragma unroll
    for (int i = 0; i < 4; ++i) {
        mrow[i] = -1e30f; lrow[i] = 0.f;
        oacc[i] = (f32x4){0.f, 0.f, 0.f, 0.f};
    }

    for (int k0 = 0; k0 < S_LEN; k0 += 64) {
        __syncthreads();
        {
            const int r  = tid >> 2;
            const int dq = (tid & 3) << 4;
            const float* src = Kh + (size_t)(k0 + r) * HDIM + dq;
            f32x4 f0 = *(const f32x4*)(src);
            f32x4 f1 = *(const f32x4*)(src + 4);
            f32x4 f2 = *(const f32x4*)(src + 8);
            f32x4 f3 = *(const f32x4*)(src + 12);
            half8 h0, h1;
#pragma unroll
            for (int j = 0; j < 4; ++j) {
                h0[j] = (_Float16)f0[j]; h0[j+4] = (_Float16)f1[j];
                h1[j] = (_Float16)f2[j]; h1[j+4] = (_Float16)f3[j];
            }
            const int swz = (r & 7) << 4;
            char* base = (char*)Klds;
            *(half8*)(base + ((r * 128 + dq * 2) ^ swz))      = h0;
            *(half8*)(base + ((r * 128 + dq * 2 + 16) ^ swz)) = h1;
        }
        {
            const int kv = tid & 63;
            const int dbase = (tid >> 6) << 4;
            const float* src = Vh + (size_t)(k0 + kv) * HDIM + dbase;
            f32x4 f0 = *(const f32x4*)(src);
            f32x4 f1 = *(const f32x4*)(src + 4);
            f32x4 f2 = *(const f32x4*)(src + 8);
            f32x4 f3 = *(const f32x4*)(src + 12);
            float vals[16];
#pragma unroll
            for (int j = 0; j < 4; ++j) {
                vals[j] = f0[j]; vals[4+j] = f1[j]; vals[8+j] = f2[j]; vals[12+j] = f3[j];
            }
            char* base = (char*)Vt;
#pragma unroll
            for (int i = 0; i < 16; ++i) {
                const int d = dbase + i;
                const int off = (d * 128 + kv * 2) ^ ((d & 7) << 4);
                *(_Float16*)(base + off) = (_Float16)vals[i];
            }
        }
        __syncthreads();

        f32x4 sacc[4];
#pragma unroll
        for (int n = 0; n < 4; ++n) sacc[n] = (f32x4){0.f,0.f,0.f,0.f};
#pragma unroll
        for (int kc = 0; kc < 2; ++kc) {
#pragma unroll
            for (int n = 0; n < 4; ++n) {
                const int off = (((16*n + c) * 128) + kc * 64 + g * 16) ^ ((c & 7) << 4);
                half8 bk = *(const half8*)((const char*)Klds + off);
                sacc[n] = __builtin_amdgcn_mfma_f32_16x16x32_f16(aq[kc], bk, sacc[n], 0, 0, 0);
            }
        }

        float sval[4][4];
        const int myq0 = q0 + wave * 16 + 4 * g;
#pragma unroll
        for (int n = 0; n < 4; ++n) {
            const int kpos = k0 + 16 * n + c;
#pragma unroll
            for (int reg = 0; reg < 4; ++reg) {
                int rel = kpos - (myq0 + reg);
                rel = rel < -128 ? -128 : (rel > 128 ? 128 : rel);
                const float bias = (float)Qrel[(wave*16 + 4*g + reg) * QRS + (rel + 128)];
                sval[n][reg] = sacc[n][reg] + bias;
            }
        }

        float mt[4];
#pragma unroll
        for (int reg = 0; reg < 4; ++reg) {
            float mp = fmaxf(fmaxf(sval[0][reg], sval[1][reg]),
                             fmaxf(sval[2][reg], sval[3][reg]));
#pragma unroll
            for (int msk = 1; msk < 16; msk <<= 1)
                mp = fmaxf(mp, __shfl_xor(mp, msk, 64));
            mt[reg] = mp;
        }

        float alpha[4], psum[4];
#pragma unroll
        for (int reg = 0; reg < 4; ++reg) {
            const float mn = fmaxf(mrow[reg], mt[reg]);
            alpha[reg] = __expf(mrow[reg] - mn);
            mrow[reg] = mn;
            psum[reg] = 0.f;
        }

        char* pbase = (char*)&Plds[wave][0];
#pragma unroll
        for (int n = 0; n < 4; ++n) {
#pragma unroll
            for (int reg = 0; reg < 4; ++reg) {
                const float pv = __expf(sval[n][reg] - mrow[reg]);
                psum[reg] += pv;
                const int row = 4 * g + reg;
                const int off = (row * 128 + (16 * n + c) * 2) ^ ((row & 7) << 4);
                *(_Float16*)(pbase + off) = (_Float16)pv;
            }
        }

#pragma unroll
        for (int reg = 0; reg < 4; ++reg) {
            float ps = psum[reg];
#pragma unroll
            for (int msk = 1; msk < 16; msk <<= 1)
                ps += __shfl_xor(ps, msk, 64);
            lrow[reg] = lrow[reg] * alpha[reg] + ps;
#pragma unroll
            for (int dn = 0; dn < 4; ++dn) oacc[dn][reg] *= alpha[reg];
        }

        asm volatile("s_waitcnt lgkmcnt(0)" ::: "memory");

        half8 ap[2];
#pragma unroll
        for (int kc = 0; kc < 2; ++kc) {
            const int off = (c * 128 + kc * 64 + g * 16) ^ ((c & 7) << 4);
            ap[kc] = *(const half8*)(pbase + off);
        }
#pragma unroll
        for (int kc = 0; kc < 2; ++kc) {
#pragma unroll
            for (int dn = 0; dn < 4; ++dn) {
                const int drow = 16 * dn + c;
                const int off = (drow * 128 + kc * 64 + g * 16) ^ ((c & 7) << 4);
                half8 bv = *(const half8*)((const char*)Vt + off);
                oacc[dn] = __builtin_amdgcn_mfma_f32_16x16x32_f16(ap[kc], bv, oacc[dn], 0, 0, 0);
            }
        }
    }

#pragma unroll
    for (int reg = 0; reg < 4; ++reg) {
        const float inv = 1.0f / lrow[reg];
        const int row = q0 + wave * 16 + 4 * g + reg;
        float* dst = Og + hoff + (size_t)row * HDIM + c;
#pragma unroll
        for (int dn = 0; dn < 4; ++dn)
            dst[16 * dn] = oacc[dn][reg] * inv;
    }
}

extern "C" void kernel_launch(void* const* d_in, const int* in_sizes, int n_in,
                              void* d_out, int out_size, void* d_ws, size_t ws_size,
                              hipStream_t stream) {
    const float* q   = (const float*)d_in[0];
    const float* k   = (const float*)d_in[1];
    const float* v   = (const float*)d_in[2];
    const float* rel = (const float*)d_in[3];
    float* out = (float*)d_out;
    (void)in_sizes; (void)n_in; (void)out_size;

    const size_t kv_bytes   = (size_t)NBH * S_LEN * HDIM * sizeof(_Float16);   // 4 MB each
    const size_t qrel_bytes = (size_t)NBH * S_LEN * QRS * sizeof(_Float16);    // ~16.9 MB
    const size_t need_full  = 2 * kv_bytes + qrel_bytes;                        // ~25.3 MB

    if (ws_size >= need_full) {
        char* p = (char*)d_ws;
        _Float16* KhB = (_Float16*)p;   p += kv_bytes;
        _Float16* VpB = (_Float16*)p;   p += kv_bytes;
        _Float16* QrB = (_Float16*)p;
        convert_kv_kernel<<<dim3(1536), 256, 0, stream>>>(k, v, KhB, VpB);
        qrel_kernel<<<dim3(512), 256, 0, stream>>>(q, rel, QrB);
        relattn_v12<<<dim3(1024), 512, 0, stream>>>(q, QrB, KhB, VpB, out);
    } else if (ws_size >= 2 * kv_bytes) {
        _Float16* KhB = (_Float16*)d_ws;
        _Float16* VpB = (_Float16*)((char*)d_ws + kv_bytes);
        convert_kv_kernel<<<dim3(1536), 256, 0, stream>>>(k, v, KhB, VpB);
        relattn_v8<<<dim3(512), 512, 0, stream>>>(q, rel, KhB, VpB, out);
    } else {
        relattn_v1<<<dim3(512), 256, 0, stream>>>(q, k, v, rel, out);
    }
}

// Round 13
// 64.894 us; speedup vs baseline: 1.3502x; 1.3502x over previous
//
#include <hip/hip_runtime.h>

typedef _Float16 half8 __attribute__((ext_vector_type(8)));
typedef _Float16 half4 __attribute__((ext_vector_type(4)));
typedef float f32x4 __attribute__((ext_vector_type(4)));

#define S_LEN 2048
#define HDIM 64
#define NT (S_LEN / 64)
#define QRS 258
#define NBH 16
#define L2E 1.44269504f
#define TSTR 72

__device__ __forceinline__ void load_lds16(const void* g, void* l) {
    __builtin_amdgcn_global_load_lds(
        (const __attribute__((address_space(1))) unsigned int*)g,
        (__attribute__((address_space(3))) unsigned int*)l, 16, 0, 0);
}

// ---- fused pre-pass (v8 format, unchanged) -----------------------------------------
// blocks 0..1023: K -> per-tile swizzled fp16 image:
//   (bh,t,kv,d) at byte (bh*32+t)*8192 + ((kv*128 + d*2) ^ ((kv&7)<<4))
// blocks 1024..1535: V -> pi-permuted transposed swizzled image:
//   chunk (d, u=4*kc+g): byte (d*128 + u*16)^((d&7)<<4);
//   content = {V[32kc+4g+r][d]}_{r=0..3} ++ {V[32kc+16+4g+r][d]}_{r=0..3}
__global__ __launch_bounds__(256)
void convert_kv_kernel(const float* __restrict__ Kg, const float* __restrict__ Vg,
                       _Float16* __restrict__ Kh, _Float16* __restrict__ Vp)
{
    __shared__ _Float16 tile[64 * TSTR];
    const int bid = blockIdx.x;
    const int tid = threadIdx.x;
    if (bid < 1024) {
        const int id = bid * 256 + tid;
        const int r  = id >> 3;
        const int d0 = (id & 7) * 8;
        const float* src = Kg + (size_t)r * HDIM + d0;
        f32x4 f0 = *(const f32x4*)(src);
        f32x4 f1 = *(const f32x4*)(src + 4);
        half8 h;
#pragma unroll
        for (int j = 0; j < 4; ++j) { h[j] = (_Float16)f0[j]; h[j+4] = (_Float16)f1[j]; }
        const int bh = r >> 11, kvg = r & 2047;
        const int t = kvg >> 6, kv = kvg & 63;
        const size_t blk = (size_t)(bh * NT + t) * 8192;
        const int off = (kv * 128 + d0 * 2) ^ ((kv & 7) << 4);
        *(half8*)((char*)Kh + blk + off) = h;
    } else {
        const int bt = bid - 1024;               // bh*32 + t
        const int bh = bt >> 5, t = bt & 31;
        {
            const int kv = tid >> 2;
            const int d0 = (tid & 3) * 16;
            const float* src = Vg + ((size_t)bh * S_LEN + t * 64 + kv) * HDIM + d0;
            f32x4 f0 = *(const f32x4*)(src);
            f32x4 f1 = *(const f32x4*)(src + 4);
            f32x4 f2 = *(const f32x4*)(src + 8);
            f32x4 f3 = *(const f32x4*)(src + 12);
            half8 h0, h1;
#pragma unroll
            for (int j = 0; j < 4; ++j) {
                h0[j] = (_Float16)f0[j]; h0[j+4] = (_Float16)f1[j];
                h1[j] = (_Float16)f2[j]; h1[j+4] = (_Float16)f3[j];
            }
            *(half8*)&tile[kv * TSTR + d0]     = h0;
            *(half8*)&tile[kv * TSTR + d0 + 8] = h1;
        }
        __syncthreads();
        {
            const int dp = tid >> 2;
            const int u0 = (tid & 3) * 2;
            char* base = (char*)Vp + (size_t)bt * 8192;
            const int dsw = (dp & 7) << 4;
#pragma unroll
            for (int ui = 0; ui < 2; ++ui) {
                const int u  = u0 + ui;
                const int kc = u >> 2, gg = u & 3;
                half8 ch;
#pragma unroll
                for (int r = 0; r < 4; ++r) {
                    ch[r]     = tile[(32*kc + 4*gg + r)      * TSTR + dp];
                    ch[4 + r] = tile[(32*kc + 16 + 4*gg + r) * TSTR + dp];
                }
                *(half8*)(base + ((dp * 128 + u * 16) ^ dsw)) = ch;
            }
        }
    }
}

// ---- main attention kernel (v13: v8 minus V staging — V direct from L2) ------------
// Wave (qs,ks): 16 q-rows x 32 kv rows of every 64-kv tile. K staged (LDS dbuf,
// gload_lds). V fragments read straight from the global pi-image at point of use,
// issued right after QK so softmax VALU hides L2 latency.
__global__ __launch_bounds__(512, 4)
void relattn_v13(const float* __restrict__ Qg, const float* __restrict__ RELg,
                 const _Float16* __restrict__ Kh, const _Float16* __restrict__ Vp,
                 float* __restrict__ Og)
{
    __shared__ __attribute__((aligned(16))) _Float16 Kbuf[2][4096];    // 16 KB (Opart at end)
    __shared__ __attribute__((aligned(16))) _Float16 Qrel[64 * QRS];   // 33 KB
    __shared__ float MLds[2][64];
    __shared__ float LLds[2][64];

    const int tid  = threadIdx.x;
    const int wave = tid >> 6;
    const int lane = tid & 63;
    const int c  = lane & 15;
    const int g  = lane >> 4;
    const int qs = wave & 3;        // q slice: rows [16qs, 16qs+16)
    const int ks = wave >> 2;       // kv half: rows [32ks, 32ks+32)

    const int wk = ((blockIdx.x & 7) << 6) + (blockIdx.x >> 3);  // XCD-chunked, 512%8==0
    const int bh = wk >> 5;
    const int q0 = (wk & 31) * 64;
    const size_t hoff = (size_t)bh * S_LEN * HDIM;

    const char* kimg = (const char*)Kh + (size_t)bh * NT * 8192;
    const char* vimg = (const char*)Vp + (size_t)bh * NT * 8192;

    // ---- prologue: stage K tile 0 ----
    load_lds16(kimg + tid * 16, (char*)&Kbuf[0][0] + tid * 16);

    // ---- Q fragment (x0.125) ----
    const int qb0 = q0 + 16 * qs;
    half8 bq[2];
#pragma unroll
    for (int kc = 0; kc < 2; ++kc) {
        const float* src = Qg + hoff + (size_t)(qb0 + c) * HDIM + kc * 32 + g * 8;
        f32x4 f0 = *(const f32x4*)(src);
        f32x4 f1 = *(const f32x4*)(src + 4);
        half8 h;
#pragma unroll
        for (int j = 0; j < 4; ++j) {
            h[j]     = (_Float16)(f0[j] * 0.125f);
            h[j + 4] = (_Float16)(f1[j] * 0.125f);
        }
        bq[kc] = h;
    }

    // ---- qrel build (ks==0 waves; wave qs builds rows [16qs..16qs+16)) ----
    if (ks == 0) {
#pragma unroll 1
        for (int t = 0; t < 17; ++t) {
            f32x4 acc = {0.f, 0.f, 0.f, 0.f};
            int r = t * 16 + c;
            if (r > 256) r = 256;
#pragma unroll
            for (int kc = 0; kc < 2; ++kc) {
                const float* src = RELg + (size_t)r * HDIM + kc * 32 + g * 8;
                f32x4 f0 = *(const f32x4*)(src);
                f32x4 f1 = *(const f32x4*)(src + 4);
                half8 b;
#pragma unroll
                for (int j = 0; j < 4; ++j) { b[j] = (_Float16)f0[j]; b[j+4] = (_Float16)f1[j]; }
                acc = __builtin_amdgcn_mfma_f32_16x16x32_f16(bq[kc], b, acc, 0, 0, 0);
            }
            const int col = t * 16 + c;
            if (col <= 256) {
#pragma unroll
                for (int reg = 0; reg < 4; ++reg)
                    Qrel[(16 * qs + 4 * g + reg) * QRS + col] = (_Float16)acc[reg];
            }
        }
    }
    __syncthreads();   // Qrel visible to all waves

    const _Float16* qr = &Qrel[(16 * qs + c) * QRS];
    const float bias_lo = (float)qr[0];
    const float bias_hi = (float)qr[256];

    const int swz = (c & 7) << 4;
    int akoff[2][2], voff[4];
#pragma unroll
    for (int n = 0; n < 2; ++n)
#pragma unroll
        for (int kc = 0; kc < 2; ++kc)
            akoff[n][kc] = (((32 * ks + 16 * n + c) * 128) + kc * 64 + g * 16) ^ swz;
#pragma unroll
    for (int dn = 0; dn < 4; ++dn)
        voff[dn] = (((16 * dn + c) * 128) + ks * 64 + g * 16) ^ swz;

    half8 ones;
#pragma unroll
    for (int j = 0; j < 8; ++j) ones[j] = (_Float16)1.0f;

    float m = -1e30f;
    f32x4 l_acc = {0.f, 0.f, 0.f, 0.f};
    f32x4 oacc[4];
#pragma unroll
    for (int i = 0; i < 4; ++i) oacc[i] = (f32x4){0.f, 0.f, 0.f, 0.f};

#define BODY(t, b) do {                                                              \
        asm volatile("s_waitcnt vmcnt(0)" ::: "memory");                             \
        __builtin_amdgcn_s_barrier();                                                \
        {   /* stage K(t+1) */                                                       \
            const int tn = ((t) + 1 < NT) ? (t) + 1 : (t);                           \
            load_lds16(kimg + (size_t)tn * 8192 + tid * 16,                          \
                       (char*)&Kbuf[(b) ^ 1][0] + tid * 16);                         \
        }                                                                            \
        const char* kb = (const char*)&Kbuf[b][0];                                   \
        const int kws = (t) * 64 + 32 * ks;                                          \
        half8 a00 = *(const half8*)(kb + akoff[0][0]);                               \
        half8 a01 = *(const half8*)(kb + akoff[0][1]);                               \
        half8 a10 = *(const half8*)(kb + akoff[1][0]);                               \
        half8 a11 = *(const half8*)(kb + akoff[1][1]);                               \
        f32x4 s0 = {0.f,0.f,0.f,0.f}, s1 = {0.f,0.f,0.f,0.f};                        \
        __builtin_amdgcn_s_setprio(1);                                               \
        s0 = __builtin_amdgcn_mfma_f32_16x16x32_f16(a00, bq[0], s0, 0, 0, 0);        \
        s1 = __builtin_amdgcn_mfma_f32_16x16x32_f16(a10, bq[0], s1, 0, 0, 0);        \
        s0 = __builtin_amdgcn_mfma_f32_16x16x32_f16(a01, bq[1], s0, 0, 0, 0);        \
        s1 = __builtin_amdgcn_mfma_f32_16x16x32_f16(a11, bq[1], s1, 0, 0, 0);        \
        __builtin_amdgcn_s_setprio(0);                                               \
        /* issue V(t) register loads EARLY (L2-resident pi-image) */                 \
        const char* vt_ = vimg + (size_t)(t) * 8192;                                 \
        half8 v0 = *(const half8*)(vt_ + voff[0]);                                   \
        half8 v1 = *(const half8*)(vt_ + voff[1]);                                   \
        half8 v2 = *(const half8*)(vt_ + voff[2]);                                   \
        half8 v3 = *(const half8*)(vt_ + voff[3]);                                   \
        float bias = 0.f;                                                            \
        float lm;                                                                    \
        if (kws + 159 <= qb0) {                                                      \
            bias = bias_lo;                                                          \
            lm = fmaxf(fmaxf(fmaxf(s0[0], s0[1]), fmaxf(s0[2], s0[3])),              \
                       fmaxf(fmaxf(s1[0], s1[1]), fmaxf(s1[2], s1[3]))) + bias;      \
        } else if (kws >= qb0 + 143) {                                               \
            bias = bias_hi;                                                          \
            lm = fmaxf(fmaxf(fmaxf(s0[0], s0[1]), fmaxf(s0[2], s0[3])),              \
                       fmaxf(fmaxf(s1[0], s1[1]), fmaxf(s1[2], s1[3]))) + bias;      \
        } else {                                                                     \
            const int base_d = kws + 4 * g - (qb0 + c) + 128;                        \
            _Pragma("unroll")                                                        \
            for (int r = 0; r < 4; ++r) {                                            \
                int i0 = base_d + r;                                                 \
                i0 = i0 < 0 ? 0 : (i0 > 256 ? 256 : i0);                             \
                int i1 = base_d + 16 + r;                                            \
                i1 = i1 < 0 ? 0 : (i1 > 256 ? 256 : i1);                             \
                s0[r] += (float)qr[i0];                                              \
                s1[r] += (float)qr[i1];                                              \
            }                                                                        \
            lm = fmaxf(fmaxf(fmaxf(s0[0], s0[1]), fmaxf(s0[2], s0[3])),              \
                       fmaxf(fmaxf(s1[0], s1[1]), fmaxf(s1[2], s1[3])));             \
        }                                                                            \
        if (!__all(lm <= m + 8.f)) {                                                 \
            float mt = lm;                                                           \
            mt = fmaxf(mt, __shfl_xor(mt, 16, 64));                                  \
            mt = fmaxf(mt, __shfl_xor(mt, 32, 64));                                  \
            const float mnew = fmaxf(m, mt);                                         \
            const float al = __builtin_amdgcn_exp2f((m - mnew) * L2E);               \
            m = mnew;                                                                \
            _Pragma("unroll")                                                        \
            for (int r = 0; r < 4; ++r) {                                            \
                const float ar = __shfl(al, 20 * g + r, 64);                         \
                l_acc[r] *= ar;                                                      \
                _Pragma("unroll")                                                    \
                for (int dn = 0; dn < 4; ++dn) oacc[dn][r] *= ar;                    \
            }                                                                        \
        }                                                                            \
        const float fold = (bias - m) * L2E;                                         \
        half8 ap;                                                                    \
        _Pragma("unroll")                                                            \
        for (int r = 0; r < 4; ++r) {                                                \
            ap[r]     = (_Float16)__builtin_amdgcn_exp2f(fmaf(s0[r], L2E, fold));    \
            ap[4 + r] = (_Float16)__builtin_amdgcn_exp2f(fmaf(s1[r], L2E, fold));    \
        }                                                                            \
        __builtin_amdgcn_s_setprio(1);                                               \
        l_acc   = __builtin_amdgcn_mfma_f32_16x16x32_f16(ap, ones, l_acc, 0, 0, 0);  \
        oacc[0] = __builtin_amdgcn_mfma_f32_16x16x32_f16(ap, v0, oacc[0], 0, 0, 0);  \
        oacc[1] = __builtin_amdgcn_mfma_f32_16x16x32_f16(ap, v1, oacc[1], 0, 0, 0);  \
        oacc[2] = __builtin_amdgcn_mfma_f32_16x16x32_f16(ap, v2, oacc[2], 0, 0, 0);  \
        oacc[3] = __builtin_amdgcn_mfma_f32_16x16x32_f16(ap, v3, oacc[3], 0, 0, 0);  \
        __builtin_amdgcn_s_setprio(0);                                               \
    } while (0)

#pragma unroll 1
    for (int tt = 0; tt < NT; tt += 2) {
        BODY(tt, 0);
        BODY(tt + 1, 1);
    }
#undef BODY

    // ---- drain, then 2-way ks merge in LDS (reuse Kbuf) ----
    asm volatile("s_waitcnt vmcnt(0)" ::: "memory");
    __syncthreads();
    {
        char* Ob = (char*)Kbuf;   // 16 KB: 2 halves x 64 rows x 64 d fp16 (row-swizzled)
#pragma unroll
        for (int r = 0; r < 4; ++r) {
            const int row = 16 * qs + 4 * g + r;
            const int rsw = (row & 7) << 4;
#pragma unroll
            for (int dn = 0; dn < 4; ++dn)
                *(_Float16*)(Ob + ks * 8192 + ((row * 128 + (16 * dn + c) * 2) ^ rsw))
                    = (_Float16)oacc[dn][r];
        }
        if (g == 0) MLds[ks][16 * qs + c] = m;
        if (c == 0) {
#pragma unroll
            for (int r = 0; r < 4; ++r)
                LLds[ks][16 * qs + 4 * g + r] = l_acc[r];
        }
        __syncthreads();

        const int row = 16 * qs + c;
        const int rsw = (c & 7) << 4;
        const float m0 = MLds[0][row], m1 = MLds[1][row];
        const float l0 = LLds[0][row], l1 = LLds[1][row];
        const float M  = fmaxf(m0, m1);
        const float w0 = __builtin_amdgcn_exp2f((m0 - M) * L2E);
        const float w1 = __builtin_amdgcn_exp2f((m1 - M) * L2E);
        const float inv = 1.0f / (l0 * w0 + l1 * w1);

        const int dof = 64 * ks + 16 * g;
        half8 o0 = *(const half8*)(Ob +        ((row * 128 + dof) ^ rsw));
        half8 o1 = *(const half8*)(Ob + 8192 + ((row * 128 + dof) ^ rsw));
        float* dst = Og + hoff + (size_t)(q0 + row) * HDIM + 32 * ks + 8 * g;
        f32x4 oA, oB;
#pragma unroll
        for (int j = 0; j < 4; ++j) {
            oA[j] = ((float)o0[j]     * w0 + (float)o1[j]     * w1) * inv;
            oB[j] = ((float)o0[4 + j] * w0 + (float)o1[4 + j] * w1) * inv;
        }
        *(f32x4*)dst = oA;
        *(f32x4*)(dst + 4) = oB;
    }
}

// ---- fallback (round-1 kernel, used if ws too small) --------------------------------
__global__ __launch_bounds__(256, 2)
void relattn_v1(const float* __restrict__ Qg, const float* __restrict__ Kg,
                const float* __restrict__ Vg, const float* __restrict__ RELg,
                float* __restrict__ Og)
{
    __shared__ _Float16 Klds[64 * HDIM];
    __shared__ _Float16 Vt[HDIM * 64];
    __shared__ _Float16 Plds[4][16 * 64];
    __shared__ _Float16 Qrel[64 * QRS];

    const int tid  = threadIdx.x;
    const int wave = tid >> 6;
    const int lane = tid & 63;
    const int c = lane & 15;
    const int g = lane >> 4;

    const int bid = blockIdx.x;
    const int bh  = bid >> 5;
    const int q0  = (bid & 31) * 64;

    const size_t hoff = (size_t)bh * S_LEN * HDIM;
    const float* Qh = Qg + hoff;
    const float* Kh = Kg + hoff;
    const float* Vh = Vg + hoff;

    const int qrow_frag = q0 + wave * 16 + c;
    half8 aq[2];
#pragma unroll
    for (int kc = 0; kc < 2; ++kc) {
        const float* src = Qh + (size_t)qrow_frag * HDIM + kc * 32 + g * 8;
        f32x4 f0 = *(const f32x4*)(src);
        f32x4 f1 = *(const f32x4*)(src + 4);
        half8 h;
#pragma unroll
        for (int j = 0; j < 4; ++j) {
            h[j]     = (_Float16)(f0[j] * 0.125f);
            h[j + 4] = (_Float16)(f1[j] * 0.125f);
        }
        aq[kc] = h;
    }

#pragma unroll 1
    for (int t = 0; t < 17; ++t) {
        f32x4 acc = {0.f, 0.f, 0.f, 0.f};
        int r = t * 16 + c;
        if (r > 256) r = 256;
#pragma unroll
        for (int kc = 0; kc < 2; ++kc) {
            const float* src = RELg + (size_t)r * HDIM + kc * 32 + g * 8;
            f32x4 f0 = *(const f32x4*)(src);
            f32x4 f1 = *(const f32x4*)(src + 4);
            half8 b;
#pragma unroll
            for (int j = 0; j < 4; ++j) { b[j] = (_Float16)f0[j]; b[j+4] = (_Float16)f1[j]; }
            acc = __builtin_amdgcn_mfma_f32_16x16x32_f16(aq[kc], b, acc, 0, 0, 0);
        }
        const int col = t * 16 + c;
        if (col <= 256) {
#pragma unroll
            for (int reg = 0; reg < 4; ++reg)
                Qrel[(wave * 16 + 4 * g + reg) * QRS + col] = (_Float16)acc[reg];
        }
    }

    float mrow[4], lrow[4];
    f32x4 oacc[4];
#pragma unroll
    for (int i = 0; i < 4; ++i) {
        mrow[i] = -1e30f; lrow[i] = 0.f;
        oacc[i] = (f32x4){0.f, 0.f, 0.f, 0.f};
    }

    for (int k0 = 0; k0 < S_LEN; k0 += 64) {
        __syncthreads();
        {
            const int r  = tid >> 2;
            const int dq = (tid & 3) << 4;
            const float* src = Kh + (size_t)(k0 + r) * HDIM + dq;
            f32x4 f0 = *(const f32x4*)(src);
            f32x4 f1 = *(const f32x4*)(src + 4);
            f32x4 f2 = *(const f32x4*)(src + 8);
            f32x4 f3 = *(const f32x4*)(src + 12);
            half8 h0, h1;
#pragma unroll
            for (int j = 0; j < 4; ++j) {
                h0[j] = (_Float16)f0[j]; h0[j+4] = (_Float16)f1[j];
                h1[j] = (_Float16)f2[j]; h1[j+4] = (_Float16)f3[j];
            }
            const int swz = (r & 7) << 4;
            char* base = (char*)Klds;
            *(half8*)(base + ((r * 128 + dq * 2) ^ swz))      = h0;
            *(half8*)(base + ((r * 128 + dq * 2 + 16) ^ swz)) = h1;
        }
        {
            const int kv = tid & 63;
            const int dbase = (tid >> 6) << 4;
            const float* src = Vh + (size_t)(k0 + kv) * HDIM + dbase;
            f32x4 f0 = *(const f32x4*)(src);
            f32x4 f1 = *(const f32x4*)(src + 4);
            f32x4 f2 = *(const f32x4*)(src + 8);
            f32x4 f3 = *(const f32x4*)(src + 12);
            float vals[16];
#pragma unroll
            for (int j = 0; j < 4; ++j) {
                vals[j] = f0[j]; vals[4+j] = f1[j]; vals[8+j] = f2[j]; vals[12+j] = f3[j];
            }
            char* base = (char*)Vt;
#pragma unroll
            for (int i = 0; i < 16; ++i) {
                const int d = dbase + i;
                const int off = (d * 128 + kv * 2) ^ ((d & 7) << 4);
                *(_Float16*)(base + off) = (_Float16)vals[i];
            }
        }
        __syncthreads();

        f32x4 sacc[4];
#pragma unroll
        for (int n = 0; n < 4; ++n) sacc[n] = (f32x4){0.f,0.f,0.f,0.f};
#pragma unroll
        for (int kc = 0; kc < 2; ++kc) {
#pragma unroll
            for (int n = 0; n < 4; ++n) {
                const int off = (((16*n + c) * 128) + kc * 64 + g * 16) ^ ((c & 7) << 4);
                half8 bk = *(const half8*)((const char*)Klds + off);
                sacc[n] = __builtin_amdgcn_mfma_f32_16x16x32_f16(aq[kc], bk, sacc[n], 0, 0, 0);
            }
        }

        float sval[4][4];
        const int myq0 = q0 + wave * 16 + 4 * g;
#pragma unroll
        for (int n = 0; n < 4; ++n) {
            const int kpos = k0 + 16 * n + c;
#pragma unroll
            for (int reg = 0; reg < 4; ++reg) {
                int rel = kpos - (myq0 + reg);
                rel = rel < -128 ? -128 : (rel > 128 ? 128 : rel);
                const float bias = (float)Qrel[(wave*16 + 4*g + reg) * QRS + (rel + 128)];
                sval[n][reg] = sacc[n][reg] + bias;
            }
        }

        float mt[4];
#pragma unroll
        for (int reg = 0; reg < 4; ++reg) {
            float mp = fmaxf(fmaxf(sval[0][reg], sval[1][reg]),
                             fmaxf(sval[2][reg], sval[3][reg]));
#pragma unroll
            for (int msk = 1; msk < 16; msk <<= 1)
                mp = fmaxf(mp, __shfl_xor(mp, msk, 64));
            mt[reg] = mp;
        }

        float alpha[4], psum[4];
#pragma unroll
        for (int reg = 0; reg < 4; ++reg) {
            const float mn = fmaxf(mrow[reg], mt[reg]);
            alpha[reg] = __expf(mrow[reg] - mn);
            mrow[reg] = mn;
            psum[reg] = 0.f;
        }

        char* pbase = (char*)&Plds[wave][0];
#pragma unroll
        for (int n = 0; n < 4; ++n) {
#pragma unroll
            for (int reg = 0; reg < 4; ++reg) {
                const float pv = __expf(sval[n][reg] - mrow[reg]);
                psum[reg] += pv;
                const int row = 4 * g + reg;
                const int off = (row * 128 + (16 * n + c) * 2) ^ ((row & 7) << 4);
                *(_Float16*)(pbase + off) = (_Float16)pv;
            }
        }

#pragma unroll
        for (int reg = 0; reg < 4; ++reg) {
            float ps = psum[reg];
#pragma unroll
            for (int msk = 1; msk < 16; msk <<= 1)
                ps += __shfl_xor(ps, msk, 64);
            lrow[reg] = lrow[reg] * alpha[reg] + ps;
#pragma unroll
            for (int dn = 0; dn < 4; ++dn) oacc[dn][reg] *= alpha[reg];
        }

        asm volatile("s_waitcnt lgkmcnt(0)" ::: "memory");

        half8 ap[2];
#pragma unroll
        for (int kc = 0; kc < 2; ++kc) {
            const int off = (c * 128 + kc * 64 + g * 16) ^ ((c & 7) << 4);
            ap[kc] = *(const half8*)(pbase + off);
        }
#pragma unroll
        for (int kc = 0; kc < 2; ++kc) {
#pragma unroll
            for (int dn = 0; dn < 4; ++dn) {
                const int drow = 16 * dn + c;
                const int off = (drow * 128 + kc * 64 + g * 16) ^ ((c & 7) << 4);
                half8 bv = *(const half8*)((const char*)Vt + off);
                oacc[dn] = __builtin_amdgcn_mfma_f32_16x16x32_f16(ap[kc], bv, oacc[dn], 0, 0, 0);
            }
        }
    }

#pragma unroll
    for (int reg = 0; reg < 4; ++reg) {
        const float inv = 1.0f / lrow[reg];
        const int row = q0 + wave * 16 + 4 * g + reg;
        float* dst = Og + hoff + (size_t)row * HDIM + c;
#pragma unroll
        for (int dn = 0; dn < 4; ++dn)
            dst[16 * dn] = oacc[dn][reg] * inv;
    }
}

extern "C" void kernel_launch(void* const* d_in, const int* in_sizes, int n_in,
                              void* d_out, int out_size, void* d_ws, size_t ws_size,
                              hipStream_t stream) {
    const float* q   = (const float*)d_in[0];
    const float* k   = (const float*)d_in[1];
    const float* v   = (const float*)d_in[2];
    const float* rel = (const float*)d_in[3];
    float* out = (float*)d_out;
    (void)in_sizes; (void)n_in; (void)out_size;

    const size_t kv_bytes = (size_t)NBH * S_LEN * HDIM * sizeof(_Float16);  // 4 MB each
    if (ws_size >= 2 * kv_bytes) {
        _Float16* KhB = (_Float16*)d_ws;
        _Float16* VpB = (_Float16*)((char*)d_ws + kv_bytes);
        convert_kv_kernel<<<dim3(1536), 256, 0, stream>>>(k, v, KhB, VpB);
        relattn_v13<<<dim3(512), 512, 0, stream>>>(q, rel, KhB, VpB, out);
    } else {
        relattn_v1<<<dim3(512), 256, 0, stream>>>(q, k, v, rel, out);
    }
}

// Round 14
// 58.584 us; speedup vs baseline: 1.4956x; 1.1077x over previous
//
#include <hip/hip_runtime.h>

typedef _Float16 half8 __attribute__((ext_vector_type(8)));
typedef _Float16 half4 __attribute__((ext_vector_type(4)));
typedef float f32x4 __attribute__((ext_vector_type(4)));

#define S_LEN 2048
#define HDIM 64
#define QBLK 64
#define KVBLK 64
#define NT (S_LEN / KVBLK)
#define QRS 258
#define NBH 16
#define L2E 1.44269504f
#define TSTR 72

__device__ __forceinline__ void load_lds16(const void* g, void* l) {
    __builtin_amdgcn_global_load_lds(
        (const __attribute__((address_space(1))) unsigned int*)g,
        (__attribute__((address_space(3))) unsigned int*)l, 16, 0, 0);
}

// ---- fused pre-pass ----------------------------------------------------------------
// blocks 0..1023: K fp32 -> Kh fp16 per-tile swizzled image:
//   (bh,t,kv,d) at byte (bh*32+t)*8192 + ((kv*128 + d*2) ^ ((kv&7)<<4))
// blocks 1024..1535: V fp32 -> Vp fp16 pi-permuted transposed image, swizzled:
//   chunk (d', u=4*kc+g) at byte bt*8192 + ((d'*128 + u*16) ^ ((d'&7)<<4))
//   content = {V[32kc+4g+r][d']}_{r=0..3} ++ {V[32kc+16+4g+r][d']}_{r=0..3}
__global__ __launch_bounds__(256)
void convert_kv_kernel(const float* __restrict__ Kg, const float* __restrict__ Vg,
                       _Float16* __restrict__ Kh, _Float16* __restrict__ Vp)
{
    __shared__ _Float16 tile[KVBLK * TSTR];
    const int bid = blockIdx.x;
    const int tid = threadIdx.x;
    if (bid < 1024) {
        const int id = bid * 256 + tid;
        const int r  = id >> 3;
        const int d0 = (id & 7) * 8;
        const float* src = Kg + (size_t)r * HDIM + d0;
        f32x4 f0 = *(const f32x4*)(src);
        f32x4 f1 = *(const f32x4*)(src + 4);
        half8 h;
#pragma unroll
        for (int j = 0; j < 4; ++j) { h[j] = (_Float16)f0[j]; h[j+4] = (_Float16)f1[j]; }
        const int bh = r >> 11, kvg = r & 2047;
        const int t = kvg >> 6, kv = kvg & 63;
        const size_t blk = (size_t)(bh * NT + t) * 8192;
        const int off = (kv * 128 + d0 * 2) ^ ((kv & 7) << 4);
        *(half8*)((char*)Kh + blk + off) = h;
    } else {
        const int bt = bid - 1024;               // bh*32 + t
        const int bh = bt >> 5, t = bt & 31;
        {
            const int kv = tid >> 2;
            const int d0 = (tid & 3) * 16;
            const float* src = Vg + ((size_t)bh * S_LEN + t * KVBLK + kv) * HDIM + d0;
            f32x4 f0 = *(const f32x4*)(src);
            f32x4 f1 = *(const f32x4*)(src + 4);
            f32x4 f2 = *(const f32x4*)(src + 8);
            f32x4 f3 = *(const f32x4*)(src + 12);
            half8 h0, h1;
#pragma unroll
            for (int j = 0; j < 4; ++j) {
                h0[j] = (_Float16)f0[j]; h0[j+4] = (_Float16)f1[j];
                h1[j] = (_Float16)f2[j]; h1[j+4] = (_Float16)f3[j];
            }
            *(half8*)&tile[kv * TSTR + d0]     = h0;
            *(half8*)&tile[kv * TSTR + d0 + 8] = h1;
        }
        __syncthreads();
        {
            const int dp = tid >> 2;             // d' = 0..63
            const int u0 = (tid & 3) * 2;
            char* base = (char*)Vp + (size_t)bt * 8192;
            const int dsw = (dp & 7) << 4;
#pragma unroll
            for (int ui = 0; ui < 2; ++ui) {
                const int u  = u0 + ui;
                const int kc = u >> 2, gg = u & 3;
                half8 ch;
#pragma unroll
                for (int r = 0; r < 4; ++r) {
                    ch[r]     = tile[(32*kc + 4*gg + r)      * TSTR + dp];
                    ch[4 + r] = tile[(32*kc + 16 + 4*gg + r) * TSTR + dp];
                }
                *(half8*)(base + ((dp * 128 + u * 16) ^ dsw)) = ch;
            }
        }
    }
}

// ---- main attention kernel (v7: 8-wave blocks, q x kv-half wave split) -------------
// Wave (qs,ks): 16 q-rows [16qs..) x 32 kv rows [32ks..) of every tile.
// One barrier per tile; staging issued after the barrier; split-kv merged in LDS.
__global__ __launch_bounds__(512, 4)
void relattn_v7(const float* __restrict__ Qg, const float* __restrict__ RELg,
                const _Float16* __restrict__ Kh, const _Float16* __restrict__ Vp,
                float* __restrict__ Og)
{
    __shared__ __attribute__((aligned(16))) _Float16 Kbuf[2][4096];    // 16 KB (also Opart at end)
    __shared__ __attribute__((aligned(16))) _Float16 Vbuf[2][4096];    // 16 KB
    __shared__ __attribute__((aligned(16))) _Float16 Qrel[QBLK * QRS]; // 33 KB
    __shared__ float MLds[2][64];
    __shared__ float LLds[2][64];

    const int tid  = threadIdx.x;
    const int wave = tid >> 6;
    const int lane = tid & 63;
    const int c  = lane & 15;
    const int g  = lane >> 4;
    const int qs = wave & 3;        // q slice: rows [16qs, 16qs+16)
    const int ks = wave >> 2;       // kv half: rows [32ks, 32ks+32) of each tile

    const int wk = ((blockIdx.x & 7) << 6) + (blockIdx.x >> 3);  // XCD-chunked, 512%8==0
    const int bh = wk >> 5;
    const int q0 = (wk & 31) * QBLK;
    const size_t hoff = (size_t)bh * S_LEN * HDIM;

    // ---- Q fragment for this wave's 16 q-rows (x0.125) ----
    const int qb0 = q0 + 16 * qs;
    half8 bq[2];
#pragma unroll
    for (int kc = 0; kc < 2; ++kc) {
        const float* src = Qg + hoff + (size_t)(qb0 + c) * HDIM + kc * 32 + g * 8;
        f32x4 f0 = *(const f32x4*)(src);
        f32x4 f1 = *(const f32x4*)(src + 4);
        half8 h;
#pragma unroll
        for (int j = 0; j < 4; ++j) {
            h[j]     = (_Float16)(f0[j] * 0.125f);
            h[j + 4] = (_Float16)(f1[j] * 0.125f);
        }
        bq[kc] = h;
    }

    // ---- qrel build (ks==0 waves only; wave qs builds rows [16qs..16qs+16)) ----
    if (ks == 0) {
#pragma unroll 1
        for (int t = 0; t < 17; ++t) {
            f32x4 acc = {0.f, 0.f, 0.f, 0.f};
            int r = t * 16 + c;
            if (r > 256) r = 256;
#pragma unroll
            for (int kc = 0; kc < 2; ++kc) {
                const float* src = RELg + (size_t)r * HDIM + kc * 32 + g * 8;
                f32x4 f0 = *(const f32x4*)(src);
                f32x4 f1 = *(const f32x4*)(src + 4);
                half8 b;
#pragma unroll
                for (int j = 0; j < 4; ++j) { b[j] = (_Float16)f0[j]; b[j+4] = (_Float16)f1[j]; }
                acc = __builtin_amdgcn_mfma_f32_16x16x32_f16(bq[kc], b, acc, 0, 0, 0);
            }
            const int col = t * 16 + c;
            if (col <= 256) {
#pragma unroll
                for (int reg = 0; reg < 4; ++reg)
                    Qrel[(16 * qs + 4 * g + reg) * QRS + col] = (_Float16)acc[reg];
            }
        }
    }

    // ---- prologue staging of tile 0 (all 512 threads: K 8KB + V 8KB) ----
    const char* kimg = (const char*)Kh + (size_t)bh * NT * 8192;
    const char* vimg = (const char*)Vp + (size_t)bh * NT * 8192;
    load_lds16(kimg + tid * 16, (char*)Kbuf + tid * 16);
    load_lds16(vimg + tid * 16, (char*)Vbuf + tid * 16);

    __syncthreads();   // Qrel visible to all waves

    const _Float16* qr = &Qrel[(16 * qs + c) * QRS];
    const float bias_lo = (float)qr[0];
    const float bias_hi = (float)qr[256];

    // loop-invariant LDS byte offsets
    const int swz = (c & 7) << 4;
    int akoff[2][2], voff[4];
#pragma unroll
    for (int n = 0; n < 2; ++n)
#pragma unroll
        for (int kc = 0; kc < 2; ++kc)
            akoff[n][kc] = (((32 * ks + 16 * n + c) * 128) + kc * 64 + g * 16) ^ swz;
#pragma unroll
    for (int dn = 0; dn < 4; ++dn)
        voff[dn] = (((16 * dn + c) * 128) + ks * 64 + g * 16) ^ swz;

    half8 ones;
#pragma unroll
    for (int j = 0; j < 8; ++j) ones[j] = (_Float16)1.0f;

    float m = -1e30f;
    f32x4 l_acc = {0.f, 0.f, 0.f, 0.f};
    f32x4 oacc[4];
#pragma unroll
    for (int i = 0; i < 4; ++i) oacc[i] = (f32x4){0.f, 0.f, 0.f, 0.f};

#define BODY(t, b) do {                                                              \
        asm volatile("s_waitcnt vmcnt(0)" ::: "memory");                             \
        __builtin_amdgcn_s_barrier();                                                \
        {                                                                            \
            const int tn = ((t) + 1 < NT) ? (t) + 1 : (t);                           \
            load_lds16(kimg + (size_t)tn * 8192 + tid * 16,                          \
                       (char*)Kbuf + ((b) ^ 1) * 8192 + tid * 16);                   \
            load_lds16(vimg + (size_t)tn * 8192 + tid * 16,                          \
                       (char*)Vbuf + ((b) ^ 1) * 8192 + tid * 16);                   \
        }                                                                            \
        const char* kb = (const char*)Kbuf + (b) * 8192;                             \
        const char* vb = (const char*)Vbuf + (b) * 8192;                             \
        const int kws = (t) * KVBLK + 32 * ks;                                       \
        half8 a00 = *(const half8*)(kb + akoff[0][0]);                               \
        half8 a01 = *(const half8*)(kb + akoff[0][1]);                               \
        half8 a10 = *(const half8*)(kb + akoff[1][0]);                               \
        half8 a11 = *(const half8*)(kb + akoff[1][1]);                               \
        f32x4 s0 = {0.f,0.f,0.f,0.f}, s1 = {0.f,0.f,0.f,0.f};                        \
        __builtin_amdgcn_s_setprio(1);                                               \
        s0 = __builtin_amdgcn_mfma_f32_16x16x32_f16(a00, bq[0], s0, 0, 0, 0);        \
        s1 = __builtin_amdgcn_mfma_f32_16x16x32_f16(a10, bq[0], s1, 0, 0, 0);        \
        s0 = __builtin_amdgcn_mfma_f32_16x16x32_f16(a01, bq[1], s0, 0, 0, 0);        \
        s1 = __builtin_amdgcn_mfma_f32_16x16x32_f16(a11, bq[1], s1, 0, 0, 0);        \
        __builtin_amdgcn_s_setprio(0);                                               \
        float bias = 0.f;                                                            \
        float lm;                                                                    \
        if (kws + 159 <= qb0) {                                                      \
            bias = bias_lo;                                                          \
            lm = fmaxf(fmaxf(fmaxf(s0[0], s0[1]), fmaxf(s0[2], s0[3])),              \
                       fmaxf(fmaxf(s1[0], s1[1]), fmaxf(s1[2], s1[3]))) + bias;      \
        } else if (kws >= qb0 + 143) {                                               \
            bias = bias_hi;                                                          \
            lm = fmaxf(fmaxf(fmaxf(s0[0], s0[1]), fmaxf(s0[2], s0[3])),              \
                       fmaxf(fmaxf(s1[0], s1[1]), fmaxf(s1[2], s1[3]))) + bias;      \
        } else {                                                                     \
            const int base_d = kws + 4 * g - (qb0 + c) + 128;                        \
            _Pragma("unroll")                                                        \
            for (int r = 0; r < 4; ++r) {                                            \
                int i0 = base_d + r;                                                 \
                i0 = i0 < 0 ? 0 : (i0 > 256 ? 256 : i0);                             \
                int i1 = base_d + 16 + r;                                            \
                i1 = i1 < 0 ? 0 : (i1 > 256 ? 256 : i1);                             \
                s0[r] += (float)qr[i0];                                              \
                s1[r] += (float)qr[i1];                                              \
            }                                                                        \
            lm = fmaxf(fmaxf(fmaxf(s0[0], s0[1]), fmaxf(s0[2], s0[3])),              \
                       fmaxf(fmaxf(s1[0], s1[1]), fmaxf(s1[2], s1[3])));             \
        }                                                                            \
        if (!__all(lm <= m + 8.f)) {                                                 \
            float mt = lm;                                                           \
            mt = fmaxf(mt, __shfl_xor(mt, 16, 64));                                  \
            mt = fmaxf(mt, __shfl_xor(mt, 32, 64));                                  \
            const float mnew = fmaxf(m, mt);                                         \
            const float al = __builtin_amdgcn_exp2f((m - mnew) * L2E);               \
            m = mnew;                                                                \
            _Pragma("unroll")                                                        \
            for (int r = 0; r < 4; ++r) {                                            \
                const float ar = __shfl(al, 20 * g + r, 64);                         \
                l_acc[r] *= ar;                                                      \
                _Pragma("unroll")                                                    \
                for (int dn = 0; dn < 4; ++dn) oacc[dn][r] *= ar;                    \
            }                                                                        \
        }                                                                            \
        const float fold = (bias - m) * L2E;                                         \
        half8 ap;                                                                    \
        _Pragma("unroll")                                                            \
        for (int r = 0; r < 4; ++r) {                                                \
            ap[r]     = (_Float16)__builtin_amdgcn_exp2f(fmaf(s0[r], L2E, fold));    \
            ap[4 + r] = (_Float16)__builtin_amdgcn_exp2f(fmaf(s1[r], L2E, fold));    \
        }                                                                            \
        half8 v0 = *(const half8*)(vb + voff[0]);                                    \
        half8 v1 = *(const half8*)(vb + voff[1]);                                    \
        half8 v2 = *(const half8*)(vb + voff[2]);                                    \
        half8 v3 = *(const half8*)(vb + voff[3]);                                    \
        __builtin_amdgcn_s_setprio(1);                                               \
        l_acc   = __builtin_amdgcn_mfma_f32_16x16x32_f16(ap, ones, l_acc, 0, 0, 0);  \
        oacc[0] = __builtin_amdgcn_mfma_f32_16x16x32_f16(ap, v0, oacc[0], 0, 0, 0);  \
        oacc[1] = __builtin_amdgcn_mfma_f32_16x16x32_f16(ap, v1, oacc[1], 0, 0, 0);  \
        oacc[2] = __builtin_amdgcn_mfma_f32_16x16x32_f16(ap, v2, oacc[2], 0, 0, 0);  \
        oacc[3] = __builtin_amdgcn_mfma_f32_16x16x32_f16(ap, v3, oacc[3], 0, 0, 0);  \
        __builtin_amdgcn_s_setprio(0);                                               \
    } while (0)

#pragma unroll 1
    for (int tt = 0; tt < NT; tt += 2) {
        BODY(tt, 0);
        BODY(tt + 1, 1);
    }
#undef BODY

    // ---- drain tail staging, then 2-way split-kv combine in LDS (reuse Kbuf) ----
    asm volatile("s_waitcnt vmcnt(0)" ::: "memory");
    __syncthreads();

    {
        char* Ob = (char*)Kbuf;   // 16 KB = 2 halves x 64 rows x 64 d fp16 (row-swizzled)
#pragma unroll
        for (int r = 0; r < 4; ++r) {
            const int row = 16 * qs + 4 * g + r;
            const int rsw = (row & 7) << 4;
#pragma unroll
            for (int dn = 0; dn < 4; ++dn)
                *(_Float16*)(Ob + ks * 8192 + ((row * 128 + (16 * dn + c) * 2) ^ rsw))
                    = (_Float16)oacc[dn][r];
        }
        if (g == 0) MLds[ks][16 * qs + c] = m;
        if (c == 0) {
#pragma unroll
            for (int r = 0; r < 4; ++r)
                LLds[ks][16 * qs + 4 * g + r] = l_acc[r];
        }
        __syncthreads();

        const int row = 16 * qs + c;         // this wave merges its 16 rows, d-half ks
        const int rsw = (c & 7) << 4;
        const float m0 = MLds[0][row], m1 = MLds[1][row];
        const float l0 = LLds[0][row], l1 = LLds[1][row];
        const float M  = fmaxf(m0, m1);
        const float w0 = __builtin_amdgcn_exp2f((m0 - M) * L2E);
        const float w1 = __builtin_amdgcn_exp2f((m1 - M) * L2E);
        const float inv = 1.0f / (l0 * w0 + l1 * w1);

        const int dof = 64 * ks + 16 * g;    // byte offset: d0 = 32ks + 8g
        half8 o0 = *(const half8*)(Ob +        ((row * 128 + dof) ^ rsw));
        half8 o1 = *(const half8*)(Ob + 8192 + ((row * 128 + dof) ^ rsw));
        float* dst = Og + hoff + (size_t)(q0 + row) * HDIM + 32 * ks + 8 * g;
        f32x4 oA, oB;
#pragma unroll
        for (int j = 0; j < 4; ++j) {
            oA[j] = ((float)o0[j]     * w0 + (float)o1[j]     * w1) * inv;
            oB[j] = ((float)o0[4 + j] * w0 + (float)o1[4 + j] * w1) * inv;
        }
        *(f32x4*)dst = oA;
        *(f32x4*)(dst + 4) = oB;
    }
}

// ---- fallback (round-1 kernel, used if ws too small) --------------------------------
__global__ __launch_bounds__(256, 2)
void relattn_v1(const float* __restrict__ Qg, const float* __restrict__ Kg,
                const float* __restrict__ Vg, const float* __restrict__ RELg,
                float* __restrict__ Og)
{
    __shared__ _Float16 Klds[KVBLK * HDIM];
    __shared__ _Float16 Vt[HDIM * KVBLK];
    __shared__ _Float16 Plds[4][16 * KVBLK];
    __shared__ _Float16 Qrel[QBLK * QRS];

    const int tid  = threadIdx.x;
    const int wave = tid >> 6;
    const int lane = tid & 63;
    const int c = lane & 15;
    const int g = lane >> 4;

    const int bid = blockIdx.x;
    const int bh  = bid >> 5;
    const int q0  = (bid & 31) * QBLK;

    const size_t hoff = (size_t)bh * S_LEN * HDIM;
    const float* Qh = Qg + hoff;
    const float* Kh = Kg + hoff;
    const float* Vh = Vg + hoff;

    const int qrow_frag = q0 + wave * 16 + c;
    half8 aq[2];
#pragma unroll
    for (int kc = 0; kc < 2; ++kc) {
        const float* src = Qh + (size_t)qrow_frag * HDIM + kc * 32 + g * 8;
        f32x4 f0 = *(const f32x4*)(src);
        f32x4 f1 = *(const f32x4*)(src + 4);
        half8 h;
#pragma unroll
        for (int j = 0; j < 4; ++j) {
            h[j]     = (_Float16)(f0[j] * 0.125f);
            h[j + 4] = (_Float16)(f1[j] * 0.125f);
        }
        aq[kc] = h;
    }

#pragma unroll 1
    for (int t = 0; t < 17; ++t) {
        f32x4 acc = {0.f, 0.f, 0.f, 0.f};
        int r = t * 16 + c;
        if (r > 256) r = 256;
#pragma unroll
        for (int kc = 0; kc < 2; ++kc) {
            const float* src = RELg + (size_t)r * HDIM + kc * 32 + g * 8;
            f32x4 f0 = *(const f32x4*)(src);
            f32x4 f1 = *(const f32x4*)(src + 4);
            half8 b;
#pragma unroll
            for (int j = 0; j < 4; ++j) { b[j] = (_Float16)f0[j]; b[j+4] = (_Float16)f1[j]; }
            acc = __builtin_amdgcn_mfma_f32_16x16x32_f16(aq[kc], b, acc, 0, 0, 0);
        }
        const int col = t * 16 + c;
        if (col <= 256) {
#pragma unroll
            for (int reg = 0; reg < 4; ++reg)
                Qrel[(wave * 16 + 4 * g + reg) * QRS + col] = (_Float16)acc[reg];
        }
    }

    float mrow[4], lrow[4];
    f32x4 oacc[4];
#pragma unroll
    for (int i = 0; i < 4; ++i) {
        mrow[i] = -1e30f; lrow[i] = 0.f;
        oacc[i] = (f32x4){0.f, 0.f, 0.f, 0.f};
    }

    for (int k0 = 0; k0 < S_LEN; k0 += KVBLK) {
        __syncthreads();
        {
            const int r  = tid >> 2;
            const int dq = (tid & 3) << 4;
            const float* src = Kh + (size_t)(k0 + r) * HDIM + dq;
            f32x4 f0 = *(const f32x4*)(src);
            f32x4 f1 = *(const f32x4*)(src + 4);
            f32x4 f2 = *(const f32x4*)(src + 8);
            f32x4 f3 = *(const f32x4*)(src + 12);
            half8 h0, h1;
#pragma unroll
            for (int j = 0; j < 4; ++j) {
                h0[j] = (_Float16)f0[j]; h0[j+4] = (_Float16)f1[j];
                h1[j] = (_Float16)f2[j]; h1[j+4] = (_Float16)f3[j];
            }
            const int swz = (r & 7) << 4;
            char* base = (char*)Klds;
            *(half8*)(base + ((r * 128 + dq * 2) ^ swz))      = h0;
            *(half8*)(base + ((r * 128 + dq * 2 + 16) ^ swz)) = h1;
        }
        {
            const int kv = tid & 63;
            const int dbase = (tid >> 6) << 4;
            const float* src = Vh + (size_t)(k0 + kv) * HDIM + dbase;
            f32x4 f0 = *(const f32x4*)(src);
            f32x4 f1 = *(const f32x4*)(src + 4);
            f32x4 f2 = *(const f32x4*)(src + 8);
            f32x4 f3 = *(const f32x4*)(src + 12);
            float vals[16];
#pragma unroll
            for (int j = 0; j < 4; ++j) {
                vals[j] = f0[j]; vals[4+j] = f1[j]; vals[8+j] = f2[j]; vals[12+j] = f3[j];
            }
            char* base = (char*)Vt;
#pragma unroll
            for (int i = 0; i < 16; ++i) {
                const int d = dbase + i;
                const int off = (d * 128 + kv * 2) ^ ((d & 7) << 4);
                *(_Float16*)(base + off) = (_Float16)vals[i];
            }
        }
        __syncthreads();

        f32x4 sacc[4];
#pragma unroll
        for (int n = 0; n < 4; ++n) sacc[n] = (f32x4){0.f,0.f,0.f,0.f};
#pragma unroll
        for (int kc = 0; kc < 2; ++kc) {
#pragma unroll
            for (int n = 0; n < 4; ++n) {
                const int off = (((16*n + c) * 128) + kc * 64 + g * 16) ^ ((c & 7) << 4);
                half8 bk = *(const half8*)((const char*)Klds + off);
                sacc[n] = __builtin_amdgcn_mfma_f32_16x16x32_f16(aq[kc], bk, sacc[n], 0, 0, 0);
            }
        }

        float sval[4][4];
        const int myq0 = q0 + wave * 16 + 4 * g;
#pragma unroll
        for (int n = 0; n < 4; ++n) {
            const int kpos = k0 + 16 * n + c;
#pragma unroll
            for (int reg = 0; reg < 4; ++reg) {
                int rel = kpos - (myq0 + reg);
                rel = rel < -128 ? -128 : (rel > 128 ? 128 : rel);
                const float bias = (float)Qrel[(wave*16 + 4*g + reg) * QRS + (rel + 128)];
                sval[n][reg] = sacc[n][reg] + bias;
            }
        }

        float mt[4];
#pragma unroll
        for (int reg = 0; reg < 4; ++reg) {
            float mp = fmaxf(fmaxf(sval[0][reg], sval[1][reg]),
                             fmaxf(sval[2][reg], sval[3][reg]));
#pragma unroll
            for (int msk = 1; msk < 16; msk <<= 1)
                mp = fmaxf(mp, __shfl_xor(mp, msk, 64));
            mt[reg] = mp;
        }

        float alpha[4], psum[4];
#pragma unroll
        for (int reg = 0; reg < 4; ++reg) {
            const float mn = fmaxf(mrow[reg], mt[reg]);
            alpha[reg] = __expf(mrow[reg] - mn);
            mrow[reg] = mn;
            psum[reg] = 0.f;
        }

        char* pbase = (char*)&Plds[wave][0];
#pragma unroll
        for (int n = 0; n < 4; ++n) {
#pragma unroll
            for (int reg = 0; reg < 4; ++reg) {
                const float pv = __expf(sval[n][reg] - mrow[reg]);
                psum[reg] += pv;
                const int row = 4 * g + reg;
                const int off = (row * 128 + (16 * n + c) * 2) ^ ((row & 7) << 4);
                *(_Float16*)(pbase + off) = (_Float16)pv;
            }
        }

#pragma unroll
        for (int reg = 0; reg < 4; ++reg) {
            float ps = psum[reg];
#pragma unroll
            for (int msk = 1; msk < 16; msk <<= 1)
                ps += __shfl_xor(ps, msk, 64);
            lrow[reg] = lrow[reg] * alpha[reg] + ps;
#pragma unroll
            for (int dn = 0; dn < 4; ++dn) oacc[dn][reg] *= alpha[reg];
        }

        asm volatile("s_waitcnt lgkmcnt(0)" ::: "memory");

        half8 ap[2];
#pragma unroll
        for (int kc = 0; kc < 2; ++kc) {
            const int off = (c * 128 + kc * 64 + g * 16) ^ ((c & 7) << 4);
            ap[kc] = *(const half8*)(pbase + off);
        }
#pragma unroll
        for (int kc = 0; kc < 2; ++kc) {
#pragma unroll
            for (int dn = 0; dn < 4; ++dn) {
                const int drow = 16 * dn + c;
                const int off = (drow * 128 + kc * 64 + g * 16) ^ ((c & 7) << 4);
                half8 bv = *(const half8*)((const char*)Vt + off);
                oacc[dn] = __builtin_amdgcn_mfma_f32_16x16x32_f16(ap[kc], bv, oacc[dn], 0, 0, 0);
            }
        }
    }

#pragma unroll
    for (int reg = 0; reg < 4; ++reg) {
        const float inv = 1.0f / lrow[reg];
        const int row = q0 + wave * 16 + 4 * g + reg;
        float* dst = Og + hoff + (size_t)row * HDIM + c;
#pragma unroll
        for (int dn = 0; dn < 4; ++dn)
            dst[16 * dn] = oacc[dn][reg] * inv;
    }
}

extern "C" void kernel_launch(void* const* d_in, const int* in_sizes, int n_in,
                              void* d_out, int out_size, void* d_ws, size_t ws_size,
                              hipStream_t stream) {
    const float* q   = (const float*)d_in[0];
    const float* k   = (const float*)d_in[1];
    const float* v   = (const float*)d_in[2];
    const float* rel = (const float*)d_in[3];
    float* out = (float*)d_out;
    (void)in_sizes; (void)n_in; (void)out_size;

    const size_t kv_bytes = (size_t)NBH * S_LEN * HDIM * sizeof(_Float16);  // 4 MB each
    if (ws_size >= 2 * kv_bytes) {
        _Float16* KhB = (_Float16*)d_ws;
        _Float16* VpB = (_Float16*)((char*)d_ws + kv_bytes);
        convert_kv_kernel<<<dim3(1536), 256, 0, stream>>>(k, v, KhB, VpB);
        relattn_v7<<<dim3(NBH * (S_LEN / QBLK)), 512, 0, stream>>>(q, rel, KhB, VpB, out);
    } else {
        relattn_v1<<<dim3(NBH * (S_LEN / QBLK)), 256, 0, stream>>>(q, k, v, rel, out);
    }
}